// Round 2
// baseline (83.869 us; speedup 1.0000x reference)
//
#include <hip/hip_runtime.h>
#include <math.h>

#define K_ 16
#define B_ 512
#define N_ 4096
#define V_ 32
#define TPB 512
#define CH (N_ / TPB)          // 8 elements per thread chunk
#define NW (TPB / 64)          // 8 waves per block
#define EPS_ 1e-13f

__global__ __launch_bounds__(TPB) void beran_kernel(
    const int* __restrict__ c_in, const float* __restrict__ delta_in,
    const float* __restrict__ c_p, const float* __restrict__ bandwidth,
    float* __restrict__ out) {
  __shared__ float p2[K_][V_];     // 2 * softmax probs
  __shared__ float wbuf[N_];       // surv values (phase 3B -> 4)
  __shared__ float sumsq[K_];
  __shared__ float wscan[NW];
  __shared__ float s_base;

  const int b = blockIdx.x;
  const int t = threadIdx.x;
  const int lane = t & 63;
  const int wid = t >> 6;

  // ---- Phase 1: per-k softmax over V=32 (one logit per thread) ----
  {
    const int k = t >> 5;          // 32 threads per concept k
    const int v = t & 31;
    float x = c_p[((size_t)k * B_ + b) * V_ + v];
    float m = x;
#pragma unroll
    for (int d = 1; d < 32; d <<= 1) m = fmaxf(m, __shfl_xor(m, d, 64));
    float e = __expf(x - m);
    float sum = e;
#pragma unroll
    for (int d = 1; d < 32; d <<= 1) sum += __shfl_xor(sum, d, 64);
    float p = e * (1.0f / sum);
    p2[k][v] = 2.0f * p;
    float ss = p * p;
#pragma unroll
    for (int d = 1; d < 32; d <<= 1) ss += __shfl_xor(ss, d, 64);
    if (v == 0) sumsq[k] = ss;
  }
  __syncthreads();
  if (t == 0) {
    float bs = 0.f;
#pragma unroll
    for (int k = 0; k < K_; k++) bs += sumsq[k];
    s_base = bs + (float)K_;       // sum_k (sum_sq + 1)
  }
  __syncthreads();
  const float base = s_base;
  float bw = bandwidth[0];
  bw = fminf(fmaxf(bw, 0.1f), 10.0f);
  const float invbw = 1.0f / bw;

  // ---- Phase 2+3A: raw weights in chunk order (registers), block scan ----
  const int start = t * CH;
  const int4* crow = (const int4*)c_in;   // row n = 16 ints = 4x int4
  float lv[CH];
  float tot = 0.f;
#pragma unroll
  for (int i = 0; i < CH; i++) {
    const int n = start + i;
    int4 a = crow[n * 4 + 0];
    int4 bb = crow[n * 4 + 1];
    int4 cc = crow[n * 4 + 2];
    int4 dd = crow[n * 4 + 3];
    float g = p2[0][a.x] + p2[1][a.y] + p2[2][a.z] + p2[3][a.w]
            + p2[4][bb.x] + p2[5][bb.y] + p2[6][bb.z] + p2[7][bb.w]
            + p2[8][cc.x] + p2[9][cc.y] + p2[10][cc.z] + p2[11][cc.w]
            + p2[12][dd.x] + p2[13][dd.y] + p2[14][dd.z] + p2[15][dd.w];
    float w = __expf(-(base - g) * invbw);
    lv[i] = w;
    tot += w;
  }
  float inc = tot;
#pragma unroll
  for (int d = 1; d < 64; d <<= 1) {
    float u = __shfl_up(inc, d, 64);
    if (lane >= d) inc += u;
  }
  if (lane == 63) wscan[wid] = inc;
  __syncthreads();
  float s = 0.f, woff = 0.f;
#pragma unroll
  for (int j = 0; j < NW; j++) {
    float v = wscan[j];
    s += v;
    if (j < wid) woff += v;
  }
  const float inv_s = (s < EPS_) ? 0.f : 1.0f / s;
  float rawp = woff + (inc - tot);       // raw exclusive prefix

  // delta chunk (coalesced float4: thread t owns [t*8, t*8+8))
  const float4* dl4 = (const float4*)delta_in;
  float dl[CH];
#pragma unroll
  for (int j = 0; j < CH / 4; j++) {
    float4 d4 = dl4[t * (CH / 4) + j];
    dl[j * 4 + 0] = d4.x; dl[j * 4 + 1] = d4.y;
    dl[j * 4 + 2] = d4.z; dl[j * 4 + 3] = d4.w;
  }
  const float thr = 1.001e-5f;           // isclose: atol + rtol*|1.0|
#pragma unroll
  for (int i = 0; i < CH; i++) {
    float sh = rawp * inv_s;             // shifted (exclusive, normalized)
    rawp += lv[i];
    float wc = rawp * inv_s;             // w_cumsum (inclusive, normalized)
    float y = 0.f;
    bool bad = (fabsf(sh - 1.f) <= thr) || (fabsf(wc - 1.f) <= thr);
    if (dl[i] != 0.f && !bad)
      y = dl[i] * (__logf(1.f - sh) - __logf(1.f - wc));
    lv[i] = y;                           // reuse register array for y
  }
  __syncthreads();                       // wscan about to be reused

  // ---- Phase 3B: block scan of y -> hazards -> surv into wbuf ----
  float tot2 = 0.f;
#pragma unroll
  for (int i = 0; i < CH; i++) tot2 += lv[i];
  float inc2 = tot2;
#pragma unroll
  for (int d = 1; d < 64; d <<= 1) {
    float u = __shfl_up(inc2, d, 64);
    if (lane >= d) inc2 += u;
  }
  if (lane == 63) wscan[wid] = inc2;
  __syncthreads();
  float hoff = 0.f;
#pragma unroll
  for (int j = 0; j < NW; j++) if (j < wid) hoff += wscan[j];
  float h = hoff + (inc2 - tot2);        // exclusive hazard prefix
#pragma unroll
  for (int i = 0; i < CH; i++) {
    h += lv[i];
    wbuf[start + i] = __expf(-h);        // surv_func
  }
  __syncthreads();

  // ---- Phase 4: outputs (coalesced) ----
  const float s2 = 1.0f - wbuf[N_ - 1];  // telescoped sum of surv_steps
  const float inv2 = (s2 < EPS_) ? 0.f : 1.0f / s2;
  float* out_s = out + (size_t)b * N_;
  float* out_t = out + (size_t)B_ * N_ + (size_t)b * N_;
  for (int n = t; n < N_; n += TPB) {
    float sv = wbuf[n];
    float pv = (n == 0) ? 1.0f : wbuf[n - 1];
    out_s[n] = sv;
    out_t[n] = (pv - sv) * inv2;
  }
}

extern "C" void kernel_launch(void* const* d_in, const int* in_sizes, int n_in,
                              void* d_out, int out_size, void* d_ws, size_t ws_size,
                              hipStream_t stream) {
  const int* c_in = (const int*)d_in[0];
  const float* delta_in = (const float*)d_in[1];
  const float* c_p = (const float*)d_in[2];
  const float* bandwidth = (const float*)d_in[3];
  float* outp = (float*)d_out;
  hipLaunchKernelGGL(beran_kernel, dim3(B_), dim3(TPB), 0, stream,
                     c_in, delta_in, c_p, bandwidth, outp);
}

// Round 3
// 76.906 us; speedup vs baseline: 1.0905x; 1.0905x over previous
//
#include <hip/hip_runtime.h>
#include <math.h>

#define K_ 16
#define B_ 512
#define N_ 4096
#define V_ 32
#define TPB 512
#define CH (N_ / TPB)          // 8 elements per thread chunk
#define NW (TPB / 64)          // 8 waves per block
#define EPS_ 1e-13f
// Conflict-free LDS swizzle: for both n = t + 512j (coalesced) and
// n = 8t + i (chunk) access patterns, bank = f(lane) hits each of the
// 32 banks exactly twice per wave -> 2-way, which is free (m136).
#define SWZ(n) ((n) + ((n) >> 5))
#define WBUF_SZ (N_ + (N_ >> 5))   // 4224 floats

__global__ __launch_bounds__(TPB) void beran_kernel(
    const int* __restrict__ c_in, const float* __restrict__ delta_in,
    const float* __restrict__ c_p, const float* __restrict__ bandwidth,
    float* __restrict__ out) {
  __shared__ float p2[K_][V_];     // 2 * softmax probs
  __shared__ float sumsq[K_];
  __shared__ float wbuf[WBUF_SZ];  // swizzled: raw w, then surv values
  __shared__ float wscan[NW];
  __shared__ float wscan2[NW];

  const int b = blockIdx.x;
  const int t = threadIdx.x;
  const int lane = t & 63;
  const int wid = t >> 6;

  // ---- Phase 1: per-k softmax over V=32 (one logit per thread) ----
  {
    const int k = t >> 5;          // 16 concepts x 32 logits = 512 threads
    const int v = t & 31;
    float x = c_p[((size_t)k * B_ + b) * V_ + v];
    float m = x;
#pragma unroll
    for (int d = 1; d < 32; d <<= 1) m = fmaxf(m, __shfl_xor(m, d, 64));
    float e = __expf(x - m);
    float sum = e;
#pragma unroll
    for (int d = 1; d < 32; d <<= 1) sum += __shfl_xor(sum, d, 64);
    float p = e * (1.0f / sum);
    p2[k][v] = 2.0f * p;
    float ss = p * p;
#pragma unroll
    for (int d = 1; d < 32; d <<= 1) ss += __shfl_xor(ss, d, 64);
    if (v == 0) sumsq[k] = ss;
  }
  __syncthreads();                 // barrier 1: p2 + sumsq ready

  // base = sum_k(sum_sq[k] + 1) via broadcast LDS reads (no serial section)
  float base = (float)K_;
#pragma unroll
  for (int k = 0; k < K_; k++) base += sumsq[k];
  float bw = fminf(fmaxf(bandwidth[0], 0.1f), 10.0f);
  const float invbw = 1.0f / bw;

  // ---- Phase 2: raw weights, COALESCED n-order -> swizzled wbuf ----
  const int4* crow = (const int4*)c_in;   // row n = 16 ints = 4x int4
#pragma unroll
  for (int j = 0; j < CH; j++) {
    const int n = t + j * TPB;     // lane stride 64 B on c_in
    int4 a = crow[n * 4 + 0];
    int4 bb = crow[n * 4 + 1];
    int4 cc = crow[n * 4 + 2];
    int4 dd = crow[n * 4 + 3];
    float g = p2[0][a.x] + p2[1][a.y] + p2[2][a.z] + p2[3][a.w]
            + p2[4][bb.x] + p2[5][bb.y] + p2[6][bb.z] + p2[7][bb.w]
            + p2[8][cc.x] + p2[9][cc.y] + p2[10][cc.z] + p2[11][cc.w]
            + p2[12][dd.x] + p2[13][dd.y] + p2[14][dd.z] + p2[15][dd.w];
    wbuf[SWZ(n)] = __expf(-(base - g) * invbw);
  }
  __syncthreads();                 // barrier 2: w ready

  // ---- Phase 3A: block scan of w; per-element xi; y = delta*xi ----
  const int start = t * CH;
  float lv[CH];
  float tot = 0.f;
#pragma unroll
  for (int i = 0; i < CH; i++) { lv[i] = wbuf[SWZ(start + i)]; tot += lv[i]; }
  float inc = tot;
#pragma unroll
  for (int d = 1; d < 64; d <<= 1) {
    float u = __shfl_up(inc, d, 64);
    if (lane >= d) inc += u;
  }
  if (lane == 63) wscan[wid] = inc;

  // delta chunk (own chunk, float4 x2) — issue before the barrier
  const float4* dl4 = (const float4*)delta_in;
  float dl[CH];
#pragma unroll
  for (int j = 0; j < CH / 4; j++) {
    float4 d4 = dl4[t * (CH / 4) + j];
    dl[j * 4 + 0] = d4.x; dl[j * 4 + 1] = d4.y;
    dl[j * 4 + 2] = d4.z; dl[j * 4 + 3] = d4.w;
  }
  __syncthreads();                 // barrier 3: wscan ready
  float s = 0.f, woff = 0.f;
#pragma unroll
  for (int j = 0; j < NW; j++) {
    float v = wscan[j];
    s += v;
    if (j < wid) woff += v;
  }
  const float inv_s = (s < EPS_) ? 0.f : 1.0f / s;
  float rawp = woff + (inc - tot);       // raw exclusive prefix

  const float thr = 1.001e-5f;           // isclose: atol + rtol*|1.0|
#pragma unroll
  for (int i = 0; i < CH; i++) {
    float sh = rawp * inv_s;             // shifted (exclusive, normalized)
    rawp += lv[i];
    float wc = rawp * inv_s;             // w_cumsum (inclusive, normalized)
    float y = 0.f;
    bool bad = (fabsf(sh - 1.f) <= thr) || (fabsf(wc - 1.f) <= thr);
    if (dl[i] != 0.f && !bad)
      y = dl[i] * (__logf(1.f - sh) - __logf(1.f - wc));
    lv[i] = y;                           // reuse register array for y
  }

  // ---- Phase 3B: block scan of y -> hazards -> surv (chunk-order) ----
  float tot2 = 0.f;
#pragma unroll
  for (int i = 0; i < CH; i++) tot2 += lv[i];
  float inc2 = tot2;
#pragma unroll
  for (int d = 1; d < 64; d <<= 1) {
    float u = __shfl_up(inc2, d, 64);
    if (lane >= d) inc2 += u;
  }
  if (lane == 63) wscan2[wid] = inc2;    // separate array: no barrier needed first
  __syncthreads();                       // barrier 4: wscan2 ready
  float hoff = 0.f, htot = 0.f;
#pragma unroll
  for (int j = 0; j < NW; j++) {
    float v = wscan2[j];
    htot += v;
    if (j < wid) hoff += v;
  }
  float h = hoff + (inc2 - tot2);        // exclusive hazard prefix
#pragma unroll
  for (int i = 0; i < CH; i++) {
    h += lv[i];
    wbuf[SWZ(start + i)] = __expf(-h);   // surv_func (own chunk: no race)
  }
  const float s2 = 1.0f - __expf(-htot); // telescoped sum of surv_steps
  const float inv2 = (s2 < EPS_) ? 0.f : 1.0f / s2;
  __syncthreads();                       // barrier 5: surv ready

  // ---- Phase 4: outputs (coalesced) ----
  float* out_s = out + (size_t)b * N_;
  float* out_t = out + (size_t)B_ * N_ + (size_t)b * N_;
#pragma unroll
  for (int j = 0; j < CH; j++) {
    const int n = t + j * TPB;
    float sv = wbuf[SWZ(n)];
    float pv = (n == 0) ? 1.0f : wbuf[SWZ(n - 1)];
    out_s[n] = sv;
    out_t[n] = (pv - sv) * inv2;
  }
}

extern "C" void kernel_launch(void* const* d_in, const int* in_sizes, int n_in,
                              void* d_out, int out_size, void* d_ws, size_t ws_size,
                              hipStream_t stream) {
  const int* c_in = (const int*)d_in[0];
  const float* delta_in = (const float*)d_in[1];
  const float* c_p = (const float*)d_in[2];
  const float* bandwidth = (const float*)d_in[3];
  float* outp = (float*)d_out;
  hipLaunchKernelGGL(beran_kernel, dim3(B_), dim3(TPB), 0, stream,
                     c_in, delta_in, c_p, bandwidth, outp);
}

// Round 4
// 74.590 us; speedup vs baseline: 1.1244x; 1.0310x over previous
//
#include <hip/hip_runtime.h>
#include <math.h>

#define K_ 16
#define B_ 512
#define N_ 4096
#define V_ 32
#define TPB 512
#define CH (N_ / TPB)          // 8 elements per thread chunk
#define NW (TPB / 64)          // 8 waves per block
#define EPS_ 1e-13f
// Conflict-free LDS swizzle: for both n = t + 512j (coalesced) and
// n = 8t + i (chunk) access patterns, each of the 32 banks is hit
// exactly twice per wave -> 2-way, which is free (m136).
#define SWZ(n) ((n) + ((n) >> 5))
#define WBUF_SZ (N_ + (N_ >> 5))   // 4224 floats

// ---- Pre-pass: pack c_in (int32 labels < 32) into bytes in d_ws ----
// Row n becomes 16 bytes -> one int4 load in the main kernel.
__global__ __launch_bounds__(256) void pack_kernel(
    const int* __restrict__ c_in, uchar4* __restrict__ packed) {
  const int i = blockIdx.x * 256 + threadIdx.x;   // 16384 words total
  int4 v = ((const int4*)c_in)[i];
  packed[i] = make_uchar4((unsigned char)v.x, (unsigned char)v.y,
                          (unsigned char)v.z, (unsigned char)v.w);
}

__global__ __launch_bounds__(TPB) void beran_kernel(
    const unsigned char* __restrict__ c8, const float* __restrict__ delta_in,
    const float* __restrict__ c_p, const float* __restrict__ bandwidth,
    float* __restrict__ out) {
  __shared__ float p2[K_][V_];     // 2 * softmax probs
  __shared__ float sumsq[K_];
  __shared__ float wbuf[WBUF_SZ];  // swizzled: raw w, then surv values
  __shared__ float wscan[NW];
  __shared__ float wscan2[NW];

  const int b = blockIdx.x;
  const int t = threadIdx.x;
  const int lane = t & 63;
  const int wid = t >> 6;

  // ---- Phase 1: per-k softmax over V=32 (one logit per thread) ----
  {
    const int k = t >> 5;          // 16 concepts x 32 logits = 512 threads
    const int v = t & 31;
    float x = c_p[((size_t)k * B_ + b) * V_ + v];
    float m = x;
#pragma unroll
    for (int d = 1; d < 32; d <<= 1) m = fmaxf(m, __shfl_xor(m, d, 64));
    float e = __expf(x - m);
    float sum = e;
#pragma unroll
    for (int d = 1; d < 32; d <<= 1) sum += __shfl_xor(sum, d, 64);
    float p = e * (1.0f / sum);
    p2[k][v] = 2.0f * p;
    float ss = p * p;
#pragma unroll
    for (int d = 1; d < 32; d <<= 1) ss += __shfl_xor(ss, d, 64);
    if (v == 0) sumsq[k] = ss;
  }
  __syncthreads();                 // barrier 1: p2 + sumsq ready

  // base = sum_k(sum_sq[k] + 1) via broadcast LDS reads (no serial section)
  float base = (float)K_;
#pragma unroll
  for (int k = 0; k < K_; k++) base += sumsq[k];
  float bw = fminf(fmaxf(bandwidth[0], 0.1f), 10.0f);
  const float invbw = 1.0f / bw;

  // ---- Phase 2: raw weights, COALESCED n-order -> swizzled wbuf ----
  // One int4 load = whole 16-label row (packed bytes).
  const int4* crow = (const int4*)c8;
#pragma unroll
  for (int j = 0; j < CH; j++) {
    const int n = t + j * TPB;     // lane stride 16 B on packed c_in
    int4 r = crow[n];
    float g;
    g  = p2[0][r.x & 31]        + p2[1][(r.x >> 8) & 31]
       + p2[2][(r.x >> 16) & 31] + p2[3][(r.x >> 24) & 31];
    g += p2[4][r.y & 31]        + p2[5][(r.y >> 8) & 31]
       + p2[6][(r.y >> 16) & 31] + p2[7][(r.y >> 24) & 31];
    g += p2[8][r.z & 31]        + p2[9][(r.z >> 8) & 31]
       + p2[10][(r.z >> 16) & 31] + p2[11][(r.z >> 24) & 31];
    g += p2[12][r.w & 31]       + p2[13][(r.w >> 8) & 31]
       + p2[14][(r.w >> 16) & 31] + p2[15][(r.w >> 24) & 31];
    wbuf[SWZ(n)] = __expf(-(base - g) * invbw);
  }
  __syncthreads();                 // barrier 2: w ready

  // ---- Phase 3A: block scan of w; per-element xi; y = delta*xi ----
  const int start = t * CH;
  float lv[CH];
  float tot = 0.f;
#pragma unroll
  for (int i = 0; i < CH; i++) { lv[i] = wbuf[SWZ(start + i)]; tot += lv[i]; }
  float inc = tot;
#pragma unroll
  for (int d = 1; d < 64; d <<= 1) {
    float u = __shfl_up(inc, d, 64);
    if (lane >= d) inc += u;
  }
  if (lane == 63) wscan[wid] = inc;

  // delta chunk (own chunk, float4 x2) — issue before the barrier
  const float4* dl4 = (const float4*)delta_in;
  float dl[CH];
#pragma unroll
  for (int j = 0; j < CH / 4; j++) {
    float4 d4 = dl4[t * (CH / 4) + j];
    dl[j * 4 + 0] = d4.x; dl[j * 4 + 1] = d4.y;
    dl[j * 4 + 2] = d4.z; dl[j * 4 + 3] = d4.w;
  }
  __syncthreads();                 // barrier 3: wscan ready
  float s = 0.f, woff = 0.f;
#pragma unroll
  for (int j = 0; j < NW; j++) {
    float v = wscan[j];
    s += v;
    if (j < wid) woff += v;
  }
  const float inv_s = (s < EPS_) ? 0.f : 1.0f / s;
  float rawp = woff + (inc - tot);       // raw exclusive prefix

  const float thr = 1.001e-5f;           // isclose: atol + rtol*|1.0|
#pragma unroll
  for (int i = 0; i < CH; i++) {
    float sh = rawp * inv_s;             // shifted (exclusive, normalized)
    rawp += lv[i];
    float wc = rawp * inv_s;             // w_cumsum (inclusive, normalized)
    float y = 0.f;
    bool bad = (fabsf(sh - 1.f) <= thr) || (fabsf(wc - 1.f) <= thr);
    if (dl[i] != 0.f && !bad)
      y = dl[i] * (__logf(1.f - sh) - __logf(1.f - wc));
    lv[i] = y;                           // reuse register array for y
  }

  // ---- Phase 3B: block scan of y -> hazards -> surv (chunk-order) ----
  float tot2 = 0.f;
#pragma unroll
  for (int i = 0; i < CH; i++) tot2 += lv[i];
  float inc2 = tot2;
#pragma unroll
  for (int d = 1; d < 64; d <<= 1) {
    float u = __shfl_up(inc2, d, 64);
    if (lane >= d) inc2 += u;
  }
  if (lane == 63) wscan2[wid] = inc2;    // separate array: no barrier needed first
  __syncthreads();                       // barrier 4: wscan2 ready
  float hoff = 0.f, htot = 0.f;
#pragma unroll
  for (int j = 0; j < NW; j++) {
    float v = wscan2[j];
    htot += v;
    if (j < wid) hoff += v;
  }
  float h = hoff + (inc2 - tot2);        // exclusive hazard prefix
#pragma unroll
  for (int i = 0; i < CH; i++) {
    h += lv[i];
    wbuf[SWZ(start + i)] = __expf(-h);   // surv_func (own chunk: no race)
  }
  const float s2 = 1.0f - __expf(-htot); // telescoped sum of surv_steps
  const float inv2 = (s2 < EPS_) ? 0.f : 1.0f / s2;
  __syncthreads();                       // barrier 5: surv ready

  // ---- Phase 4: outputs (coalesced) ----
  float* out_s = out + (size_t)b * N_;
  float* out_t = out + (size_t)B_ * N_ + (size_t)b * N_;
#pragma unroll
  for (int j = 0; j < CH; j++) {
    const int n = t + j * TPB;
    float sv = wbuf[SWZ(n)];
    float pv = (n == 0) ? 1.0f : wbuf[SWZ(n - 1)];
    out_s[n] = sv;
    out_t[n] = (pv - sv) * inv2;
  }
}

extern "C" void kernel_launch(void* const* d_in, const int* in_sizes, int n_in,
                              void* d_out, int out_size, void* d_ws, size_t ws_size,
                              hipStream_t stream) {
  const int* c_in = (const int*)d_in[0];
  const float* delta_in = (const float*)d_in[1];
  const float* c_p = (const float*)d_in[2];
  const float* bandwidth = (const float*)d_in[3];
  float* outp = (float*)d_out;
  unsigned char* packed = (unsigned char*)d_ws;   // 64 KB used of d_ws

  // Pack 4096x16 int32 labels -> bytes (16384 words, 64 blocks x 256)
  hipLaunchKernelGGL(pack_kernel, dim3((N_ * K_ / 4) / 256), dim3(256), 0, stream,
                     c_in, (uchar4*)packed);
  hipLaunchKernelGGL(beran_kernel, dim3(B_), dim3(TPB), 0, stream,
                     packed, delta_in, c_p, bandwidth, outp);
}